// Round 13
// baseline (376.356 us; speedup 1.0000x reference)
//
#include <hip/hip_runtime.h>

// Linear-chain CRF log-partition, B=64, S=1024, T=128.
//
// r24 = r23 + __attribute__((amdgpu_num_vgpr(128))) — the DIRECT register
// allocation request, the one lever not yet tried.
//
// r23 post-mortem: NULL (counters identical to r22: VGPR=64, WRITE=128MB
// scratch, seg 293us, MfmaUtil 42%). waves_per_eu(4,4) and the 16-operand
// pin changed nothing: the pin forces residency only AT the asm point;
// the allocator still shuttles EA through scratch across the MFMA region
// (~64 scratch loads/wave-step -> measured 2800 cyc/block-step vs ~1350
// of real DS+MFMA work). EA demand (64 rows x 128 K x f16 = 64 VGPR) is
// intrinsic to the DS-optimal geometry; the only question is making the
// backend allocate 128. Indirect levers failed 5x; amdgpu_num_vgpr(128)
// is the explicit per-kernel request.
//
// HARD GATES: VGPR_Count=128 (64 again = attribute path dead -> r25
// pivots geometry); WRITE_SIZE ~33MB; seg 180-220us; MfmaUtil 55-65%.
//
// Geometry (unchanged from r22/r23, passed absmax 0.0): 1024 blocks
// (64b x 16g), 512 thr = 8 waves = 2 row-groups x 4 col-groups; wave owns
// a 64x32 C quadrant; B dbuf 2x32KB swizzled LDS; exp(em) staged once per
// block as f16 into a 16KB LDS U-chunk; one barrier per step.
// Workspace: 32 MB.

typedef _Float16 h8  __attribute__((ext_vector_type(8)));
typedef _Float16 hv2 __attribute__((ext_vector_type(2)));
typedef float    f4  __attribute__((ext_vector_type(4)));
typedef unsigned u4v __attribute__((ext_vector_type(4)));

#define B_  64
#define S_  1024
#define T_  128
#define G_  16
#define PAD_IDX 0
#define EOS_IDX 3
#define BOT_IDX 1
#define GHAT         5.35f
#define EXP_NEG_GHAT 0.004736892f   // e^{-5.35}

// swizzled LDS byte offset for B element (n = col 0..127, ks = k>>3)
__device__ __forceinline__ int baddr16(int n, int ks) {
  return n * 256 + (((ks ^ n) & 15) << 4);
}

// ---------------- kernel 1: per-segment matrix product ----------------
__global__ __launch_bounds__(512)
__attribute__((amdgpu_waves_per_eu(4, 4)))
__attribute__((amdgpu_num_vgpr(128)))
void crf_seg_kernel(const int* __restrict__ W,
                    const float* __restrict__ emissions,
                    const float* __restrict__ transitions,
                    _Float16* __restrict__ ws)
{
  const int b = blockIdx.x, g = blockIdx.y;
  const int tid  = threadIdx.x;     // 0..511 — eight waves
  const int w    = tid >> 6;
  const int rg   = w >> 2;          // row group 0..1 -> rows [64rg, 64rg+64)
  const int cg   = w & 3;           // col group 0..3 -> cols [32cg, 32cg+32)
  const int lane = tid & 63;
  const int lr   = lane & 15;       // row-in-tile (A) / col (B,C)
  const int lg   = lane >> 4;       // 8-K group (A,B) / 4-row group (C)

  __shared__ __align__(16) char     bbuf[2][32768];   // B operand, dbuf
  __shared__ __align__(16) _Float16 uld[64 * T_];     // exp(em) chunk, f16

  // --- segment activity mask (identical in all waves)
  int tok = W[b * S_ + g * 64 + lane];
  unsigned long long mask = __ballot((tok != PAD_IDX) & (tok != EOS_IDX));
  if (g == 0) mask &= ~1ull;                      // i==0 is never consumed

  const size_t segoff = ((size_t)(b * G_ + g)) << 14;   // 16384 f16/segment

  if (mask == 0ull) {                             // empty segment: S_g = I
    int r = tid >> 2, c0 = (tid & 3) << 5;
    #pragma unroll
    for (int e8 = 0; e8 < 4; ++e8) {
      h8 v;
      #pragma unroll
      for (int e = 0; e < 8; ++e)
        v[e] = (r == c0 + e8 * 8 + e) ? (_Float16)1.f : (_Float16)0.f;
      *(h8*)(ws + segoff + (size_t)r * T_ + c0 + e8 * 8) = v;
    }
    return;
  }

  // --- A operand: E' = exp(trans)*e^-GHAT, rows [64rg, 64rg+64)
  // EA[rtl][kb] = A[row = 64rg+16rtl+lr][k = kb*32 + lg*8 + j]  (64 VGPRs)
  u4v EA[4][4];
  #pragma unroll
  for (int rtl = 0; rtl < 4; ++rtl) {
    const int row = 64 * rg + 16 * rtl + lr;
    #pragma unroll
    for (int kb = 0; kb < 4; ++kb) {
      const float4* tp = (const float4*)(transitions + (size_t)row * T_ + kb * 32 + lg * 8);
      float4 x = tp[0], y = tp[1];
      h8 f;
      f[0] = (_Float16)(__expf(x.x) * EXP_NEG_GHAT);
      f[1] = (_Float16)(__expf(x.y) * EXP_NEG_GHAT);
      f[2] = (_Float16)(__expf(x.z) * EXP_NEG_GHAT);
      f[3] = (_Float16)(__expf(x.w) * EXP_NEG_GHAT);
      f[4] = (_Float16)(__expf(y.x) * EXP_NEG_GHAT);
      f[5] = (_Float16)(__expf(y.y) * EXP_NEG_GHAT);
      f[6] = (_Float16)(__expf(y.z) * EXP_NEG_GHAT);
      f[7] = (_Float16)(__expf(y.w) * EXP_NEG_GHAT);
      EA[rtl][kb] = __builtin_bit_cast(u4v, f);
    }
  }

  // --- stage U = f16(exp(em-chunk)) into LDS (coalesced, once per block)
  {
    const float4* emc = (const float4*)(emissions + ((size_t)b * S_ + g * 64) * T_);
    #pragma unroll
    for (int k = 0; k < 4; ++k) {
      int f = tid + k * 512;                     // float4 index in [0, 2048)
      float4 v = emc[f];
      uint2 d;
      d.x = __builtin_bit_cast(unsigned,
              __builtin_amdgcn_cvt_pkrtz(__expf(v.x), __expf(v.y)));
      d.y = __builtin_bit_cast(unsigned,
              __builtin_amdgcn_cvt_pkrtz(__expf(v.z), __expf(v.w)));
      *(uint2*)&uld[f * 4] = d;
    }
  }
  // zero Bbuf[0] (diag init is sparse)
  {
    char* bz = &bbuf[0][0] + tid * 64;
    #pragma unroll
    for (int r = 0; r < 4; ++r) *(uint4*)(bz + r * 16) = uint4{0u,0u,0u,0u};
  }
  __syncthreads();

  // --- init Bbuf[0] = diag(U[hib])
  const int hib = 63 - __builtin_clzll(mask);
  if (tid < T_) {
    _Float16 u = uld[hib * T_ + tid];
    *(_Float16*)(&bbuf[0][tid * 256 + (((tid >> 3) ^ tid) & 15) * 16 + (tid & 7) * 2]) = u;
  }

  unsigned long long rem = mask & ~(1ull << hib);
  int inb = rem ? (63 - __builtin_clzll(rem)) : -1;

  int p = 0;
  f4 acc[4][2];
  for (;;) {
    // SINGLE pin: all 16 EA frags (64 regs) simultaneously resident,
    // non-rematerializable; zero instructions.
    asm volatile("" : "+v"(EA[0][0]), "+v"(EA[0][1]), "+v"(EA[0][2]), "+v"(EA[0][3]),
                      "+v"(EA[1][0]), "+v"(EA[1][1]), "+v"(EA[1][2]), "+v"(EA[1][3]),
                      "+v"(EA[2][0]), "+v"(EA[2][1]), "+v"(EA[2][2]), "+v"(EA[2][3]),
                      "+v"(EA[3][0]), "+v"(EA[3][1]), "+v"(EA[3][2]), "+v"(EA[3][3]));

    __syncthreads();                              // Bbuf[p] ready

    #pragma unroll
    for (int rtl = 0; rtl < 4; ++rtl)
      #pragma unroll
      for (int ct = 0; ct < 2; ++ct) acc[rtl][ct] = f4{0.f, 0.f, 0.f, 0.f};

    #pragma unroll
    for (int kb = 0; kb < 4; ++kb) {
      #pragma unroll
      for (int ct = 0; ct < 2; ++ct) {
        const int n = 32 * cg + 16 * ct + lr;
        h8 bf = *(const h8*)(&bbuf[p][baddr16(n, kb * 4 + lg)]);
        #pragma unroll
        for (int rtl = 0; rtl < 4; ++rtl)
          acc[rtl][ct] = __builtin_amdgcn_mfma_f32_16x16x32_f16(
              __builtin_bit_cast(h8, EA[rtl][kb]), bf, acc[rtl][ct], 0, 0, 0);
      }
    }

    if (inb < 0) break;                           // acc = S_g quadrant, done

    const int step = inb;
    rem &= ~(1ull << inb);
    const int inn = rem ? (63 - __builtin_clzll(rem)) : -1;

    // publish Bbuf[p^1] = diag(U[step]) * acc  (f16, swizzled)
    #pragma unroll
    for (int rtl = 0; rtl < 4; ++rtl) {
      const int k0 = 64 * rg + 16 * rtl + 4 * lg;
      uint2 up = *(const uint2*)&uld[step * T_ + k0];   // broadcast b64
      hv2 u01 = __builtin_bit_cast(hv2, up.x);
      hv2 u23 = __builtin_bit_cast(hv2, up.y);
      #pragma unroll
      for (int ct = 0; ct < 2; ++ct) {
        const int n = 32 * cg + 16 * ct + lr;
        f4 c = acc[rtl][ct];
        hv2 lo = __builtin_bit_cast(hv2,
                   __builtin_amdgcn_cvt_pkrtz(c[0], c[1])) * u01;
        hv2 hi = __builtin_bit_cast(hv2,
                   __builtin_amdgcn_cvt_pkrtz(c[2], c[3])) * u23;
        uint2 d;
        d.x = __builtin_bit_cast(unsigned, lo);
        d.y = __builtin_bit_cast(unsigned, hi);
        *(uint2*)(&bbuf[p ^ 1][n * 256 + (((k0 >> 3) ^ n) & 15) * 16 + (k0 & 7) * 2]) = d;
      }
    }
    p ^= 1;
    inb = inn;
  }

  // --- store S_g quadrant (unscaled acc) to workspace, row-major f16
  #pragma unroll
  for (int rtl = 0; rtl < 4; ++rtl) {
    const int k0 = 64 * rg + 16 * rtl + 4 * lg;
    #pragma unroll
    for (int ct = 0; ct < 2; ++ct) {
      const int n = 32 * cg + 16 * ct + lr;
      #pragma unroll
      for (int r = 0; r < 4; ++r)
        ws[segoff + (size_t)(k0 + r) * T_ + n] = (_Float16)acc[rtl][ct][r];
    }
  }
}

// ---------------- kernel 2: combine segments + epilogue ----------------
__global__ __launch_bounds__(128)
void crf_combine_kernel(const int* __restrict__ W,
                        const float* __restrict__ emissions,
                        const float* __restrict__ transitions,
                        const _Float16* __restrict__ ws,
                        float* __restrict__ out)
{
  const int b = blockIdx.x, t = threadIdx.x;
  __shared__ float qv[T_];
  __shared__ float redf[128];
  __shared__ int   redi[128];

  qv[t] = 1.0f;
  __syncthreads();

  // apply S_15 first, S_0 last:  q = S_0 S_1 ... S_15 * 1
  for (int g = G_ - 1; g >= 0; --g) {
    const _Float16* Sg = ws + (((size_t)(b * G_ + g)) << 14) + (size_t)t * T_;
    float acc = 0.f;
    #pragma unroll
    for (int j8 = 0; j8 < 16; ++j8) {
      h8 v = *(const h8*)(Sg + j8 * 8);
      float4 q0 = *(const float4*)&qv[j8 * 8];
      float4 q1 = *(const float4*)&qv[j8 * 8 + 4];
      acc += (float)v[0] * q0.x + (float)v[1] * q0.y
           + (float)v[2] * q0.z + (float)v[3] * q0.w
           + (float)v[4] * q1.x + (float)v[5] * q1.y
           + (float)v[6] * q1.z + (float)v[7] * q1.w;
    }
    __syncthreads();
    qv[t] = acc;
    __syncthreads();
  }

  // count of active steps (i in [1,1023]) for the GHAT compensation
  int cnt = 0;
  #pragma unroll
  for (int c = 0; c < 8; ++c) {
    int i = c * 128 + t;
    if (i >= 1) {
      int tk = W[b * S_ + i];
      cnt += ((tk != PAD_IDX) & (tk != EOS_IDX)) ? 1 : 0;
    }
  }

  float term = __expf(transitions[BOT_IDX * T_ + t]
                      + emissions[(size_t)b * S_ * T_ + t]) * qv[t];
  redf[t] = term;
  redi[t] = cnt;
  __syncthreads();
  #pragma unroll
  for (int off = 64; off > 0; off >>= 1) {
    if (t < off) { redf[t] += redf[t + off]; redi[t] += redi[t + off]; }
    __syncthreads();
  }
  if (t == 0) out[b] = GHAT * (float)redi[0] + logf(redf[0]);
}

extern "C" void kernel_launch(void* const* d_in, const int* in_sizes, int n_in,
                              void* d_out, int out_size, void* d_ws, size_t ws_size,
                              hipStream_t stream) {
  const int*   W     = (const int*)d_in[0];
  const float* em    = (const float*)d_in[1];
  const float* trans = (const float*)d_in[2];
  float*       out   = (float*)d_out;
  _Float16*    wsp   = (_Float16*)d_ws;          // needs 32 MB
  (void)in_sizes; (void)n_in; (void)out_size; (void)ws_size;

  crf_seg_kernel<<<dim3(B_, G_), 512, 0, stream>>>(W, em, trans, wsp);
  crf_combine_kernel<<<B_, 128, 0, stream>>>(W, em, trans, wsp, out);
}

// Round 14
// 345.387 us; speedup vs baseline: 1.0897x; 1.0897x over previous
//
#include <hip/hip_runtime.h>

// Linear-chain CRF log-partition, B=64, S=1024, T=128.
//
// r25 = the 64-row-wave DS-halving geometry repackaged into 256-thread
// blocks (where the allocator grants ~132 VGPRs) via a 2-WAY column
// split across blocks.
//
// r22-r24 verdict: 512-thread kernels get 64 VGPRs, immovably (launch_
// bounds(,4), waves_per_eu(4,4), amdgpu_num_vgpr(128), asm pins - all
// null; EA spilled, WRITE_SIZE 128MB, seg stuck at ~291us with MfmaUtil
// 42% = exactly the 110us MFMA floor + spill stall). 256-thread kernels
// historically get what they need up to ~132 (r11:132, r19:96).
//
// r25 geometry: grid (64 b x 16 g x 2 ch) = 2048 blocks x 256 thr;
// block owns cols [64ch, 64ch+64) of the running product slice
// (column slices evolve independently). 4 waves = 2 rg x 2 cg; wave owns
// a 64x32 C quadrant. Demand: EA 64 + acc 32 + transients ~= 120 <= 132.
// Unlike r20's 8-way split (em fetch x8 = disaster), 2-way costs only
// +16MB HBM (~3us) and exp runs once per block into the LDS U-chunk.
//
// DS per full step (2 blocks): 64KB read + 32KB write = 96KB vs r19's
// 160KB. LDS = 2x16KB B-dbuf + 16KB U = 48KB -> 3 blocks/CU.
// Floors: DS ~143us, MFMA 110us.
//
// GATES: VGPR ~110-128 AND WRITE ~33MB (either fails -> 64-row waves
// dead, r26 = r19+U-LDS); seg 160-210us; MfmaUtil 55-70%.
//
// Numerics IDENTICAL to r22/r23/r24 (all passed absmax 0.0).
// Workspace: 32 MB.

typedef _Float16 h8  __attribute__((ext_vector_type(8)));
typedef _Float16 hv2 __attribute__((ext_vector_type(2)));
typedef float    f4  __attribute__((ext_vector_type(4)));
typedef unsigned u4v __attribute__((ext_vector_type(4)));

#define B_  64
#define S_  1024
#define T_  128
#define G_  16
#define PAD_IDX 0
#define EOS_IDX 3
#define BOT_IDX 1
#define GHAT         5.35f
#define EXP_NEG_GHAT 0.004736892f   // e^{-5.35}

// swizzled LDS byte offset for B-slice element (n = LOCAL col 0..63,
// ks = k>>3, k = global row 0..127). 256 B per column.
__device__ __forceinline__ int baddr16(int n, int ks) {
  return n * 256 + (((ks ^ n) & 15) << 4);
}

// ---------------- kernel 1: per-segment column-slice product ----------------
__global__ __launch_bounds__(256)
void crf_seg_kernel(const int* __restrict__ W,
                    const float* __restrict__ emissions,
                    const float* __restrict__ transitions,
                    _Float16* __restrict__ ws)
{
  const int b = blockIdx.x, g = blockIdx.y, ch = blockIdx.z;
  const int tid  = threadIdx.x;     // 0..255 — four waves
  const int w    = tid >> 6;
  const int rg   = w >> 1;          // row group 0..1 -> rows [64rg, 64rg+64)
  const int cg   = w & 1;           // col group 0..1 -> local cols [32cg,+32)
  const int lane = tid & 63;
  const int lr   = lane & 15;       // row-in-tile (A) / col (B,C)
  const int lg   = lane >> 4;       // 8-K group (A,B) / 4-row group (C)

  __shared__ __align__(16) char     bbuf[2][16384];   // 64-col B slice, dbuf
  __shared__ __align__(16) _Float16 uld[64 * T_];     // exp(em) chunk, f16

  // --- segment activity mask (identical in all waves)
  int tok = W[b * S_ + g * 64 + lane];
  unsigned long long mask = __ballot((tok != PAD_IDX) & (tok != EOS_IDX));
  if (g == 0) mask &= ~1ull;                      // i==0 is never consumed

  const size_t segoff = ((size_t)(b * G_ + g)) << 14;   // 16384 f16/segment

  if (mask == 0ull) {                             // empty: S_g slice = I slice
    int r = tid >> 1, c0 = 64 * ch + (tid & 1) * 32;
    #pragma unroll
    for (int e8 = 0; e8 < 4; ++e8) {
      h8 v;
      #pragma unroll
      for (int e = 0; e < 8; ++e)
        v[e] = (r == c0 + e8 * 8 + e) ? (_Float16)1.f : (_Float16)0.f;
      *(h8*)(ws + segoff + (size_t)r * T_ + c0 + e8 * 8) = v;
    }
    return;
  }

  // --- A operand: E' = exp(trans)*e^-GHAT, rows [64rg, 64rg+64)
  // EA[rtl][kb] = A[row = 64rg+16rtl+lr][k = kb*32 + lg*8 + j]  (64 VGPRs)
  u4v EA[4][4];
  #pragma unroll
  for (int rtl = 0; rtl < 4; ++rtl) {
    const int row = 64 * rg + 16 * rtl + lr;
    #pragma unroll
    for (int kb = 0; kb < 4; ++kb) {
      const float4* tp = (const float4*)(transitions + (size_t)row * T_ + kb * 32 + lg * 8);
      float4 x = tp[0], y = tp[1];
      h8 f;
      f[0] = (_Float16)(__expf(x.x) * EXP_NEG_GHAT);
      f[1] = (_Float16)(__expf(x.y) * EXP_NEG_GHAT);
      f[2] = (_Float16)(__expf(x.z) * EXP_NEG_GHAT);
      f[3] = (_Float16)(__expf(x.w) * EXP_NEG_GHAT);
      f[4] = (_Float16)(__expf(y.x) * EXP_NEG_GHAT);
      f[5] = (_Float16)(__expf(y.y) * EXP_NEG_GHAT);
      f[6] = (_Float16)(__expf(y.z) * EXP_NEG_GHAT);
      f[7] = (_Float16)(__expf(y.w) * EXP_NEG_GHAT);
      EA[rtl][kb] = __builtin_bit_cast(u4v, f);
    }
  }

  // --- stage U = f16(exp(em-chunk)) into LDS (coalesced, once per block)
  {
    const float4* emc = (const float4*)(emissions + ((size_t)b * S_ + g * 64) * T_);
    #pragma unroll
    for (int k = 0; k < 8; ++k) {
      int f = tid + k * 256;                     // float4 index in [0, 2048)
      float4 v = emc[f];
      uint2 d;
      d.x = __builtin_bit_cast(unsigned,
              __builtin_amdgcn_cvt_pkrtz(__expf(v.x), __expf(v.y)));
      d.y = __builtin_bit_cast(unsigned,
              __builtin_amdgcn_cvt_pkrtz(__expf(v.z), __expf(v.w)));
      *(uint2*)&uld[f * 4] = d;
    }
  }
  // zero Bbuf[0] (diag init is sparse): 16 KB / 256 thr = 64 B each
  {
    char* bz = &bbuf[0][0] + tid * 64;
    #pragma unroll
    for (int r = 0; r < 4; ++r) *(uint4*)(bz + r * 16) = uint4{0u,0u,0u,0u};
  }
  __syncthreads();

  // --- init Bbuf[0] = diag(U[hib]) slice: local col n -> global row 64ch+n
  const int hib = 63 - __builtin_clzll(mask);
  if (tid < 64) {
    int kdiag = 64 * ch + tid;
    _Float16 u = uld[hib * T_ + kdiag];
    *(_Float16*)(&bbuf[0][baddr16(tid, kdiag >> 3) + (kdiag & 7) * 2]) = u;
  }

  unsigned long long rem = mask & ~(1ull << hib);
  int inb = rem ? (63 - __builtin_clzll(rem)) : -1;

  int p = 0;
  f4 acc[4][2];
  for (;;) {
    // single pin: all 16 EA frags (64 regs) simultaneously resident
    asm volatile("" : "+v"(EA[0][0]), "+v"(EA[0][1]), "+v"(EA[0][2]), "+v"(EA[0][3]),
                      "+v"(EA[1][0]), "+v"(EA[1][1]), "+v"(EA[1][2]), "+v"(EA[1][3]),
                      "+v"(EA[2][0]), "+v"(EA[2][1]), "+v"(EA[2][2]), "+v"(EA[2][3]),
                      "+v"(EA[3][0]), "+v"(EA[3][1]), "+v"(EA[3][2]), "+v"(EA[3][3]));

    __syncthreads();                              // Bbuf[p] ready (and diag)

    #pragma unroll
    for (int rtl = 0; rtl < 4; ++rtl)
      #pragma unroll
      for (int ct = 0; ct < 2; ++ct) acc[rtl][ct] = f4{0.f, 0.f, 0.f, 0.f};

    #pragma unroll
    for (int kb = 0; kb < 4; ++kb) {
      #pragma unroll
      for (int ct = 0; ct < 2; ++ct) {
        const int n = 32 * cg + 16 * ct + lr;     // local col
        h8 bf = *(const h8*)(&bbuf[p][baddr16(n, kb * 4 + lg)]);
        #pragma unroll
        for (int rtl = 0; rtl < 4; ++rtl)
          acc[rtl][ct] = __builtin_amdgcn_mfma_f32_16x16x32_f16(
              __builtin_bit_cast(h8, EA[rtl][kb]), bf, acc[rtl][ct], 0, 0, 0);
      }
    }

    if (inb < 0) break;                           // acc = S_g slice quadrant

    const int step = inb;
    rem &= ~(1ull << inb);
    const int inn = rem ? (63 - __builtin_clzll(rem)) : -1;

    // publish Bbuf[p^1] = diag(U[step]) * acc  (f16, swizzled)
    #pragma unroll
    for (int rtl = 0; rtl < 4; ++rtl) {
      const int k0 = 64 * rg + 16 * rtl + 4 * lg; // global row of acc[...][0]
      uint2 up = *(const uint2*)&uld[step * T_ + k0];   // broadcast b64
      hv2 u01 = __builtin_bit_cast(hv2, up.x);
      hv2 u23 = __builtin_bit_cast(hv2, up.y);
      #pragma unroll
      for (int ct = 0; ct < 2; ++ct) {
        const int n = 32 * cg + 16 * ct + lr;
        f4 c = acc[rtl][ct];
        hv2 lo = __builtin_bit_cast(hv2,
                   __builtin_amdgcn_cvt_pkrtz(c[0], c[1])) * u01;
        hv2 hi = __builtin_bit_cast(hv2,
                   __builtin_amdgcn_cvt_pkrtz(c[2], c[3])) * u23;
        uint2 d;
        d.x = __builtin_bit_cast(unsigned, lo);
        d.y = __builtin_bit_cast(unsigned, hi);
        *(uint2*)(&bbuf[p ^ 1][baddr16(n, k0 >> 3) + (k0 & 7) * 2]) = d;
      }
    }
    p ^= 1;
    inb = inn;
  }

  // --- store S_g slice (unscaled acc) to workspace, row-major f16
  #pragma unroll
  for (int rtl = 0; rtl < 4; ++rtl) {
    const int k0 = 64 * rg + 16 * rtl + 4 * lg;
    #pragma unroll
    for (int ct = 0; ct < 2; ++ct) {
      const int n = 64 * ch + 32 * cg + 16 * ct + lr;   // global col
      #pragma unroll
      for (int r = 0; r < 4; ++r)
        ws[segoff + (size_t)(k0 + r) * T_ + n] = (_Float16)acc[rtl][ct][r];
    }
  }
}

// ---------------- kernel 2: combine segments + epilogue ----------------
__global__ __launch_bounds__(128)
void crf_combine_kernel(const int* __restrict__ W,
                        const float* __restrict__ emissions,
                        const float* __restrict__ transitions,
                        const _Float16* __restrict__ ws,
                        float* __restrict__ out)
{
  const int b = blockIdx.x, t = threadIdx.x;
  __shared__ float qv[T_];
  __shared__ float redf[128];
  __shared__ int   redi[128];

  qv[t] = 1.0f;
  __syncthreads();

  // apply S_15 first, S_0 last:  q = S_0 S_1 ... S_15 * 1
  for (int g = G_ - 1; g >= 0; --g) {
    const _Float16* Sg = ws + (((size_t)(b * G_ + g)) << 14) + (size_t)t * T_;
    float acc = 0.f;
    #pragma unroll
    for (int j8 = 0; j8 < 16; ++j8) {
      h8 v = *(const h8*)(Sg + j8 * 8);
      float4 q0 = *(const float4*)&qv[j8 * 8];
      float4 q1 = *(const float4*)&qv[j8 * 8 + 4];
      acc += (float)v[0] * q0.x + (float)v[1] * q0.y
           + (float)v[2] * q0.z + (float)v[3] * q0.w
           + (float)v[4] * q1.x + (float)v[5] * q1.y
           + (float)v[6] * q1.z + (float)v[7] * q1.w;
    }
    __syncthreads();
    qv[t] = acc;
    __syncthreads();
  }

  // count of active steps (i in [1,1023]) for the GHAT compensation
  int cnt = 0;
  #pragma unroll
  for (int c = 0; c < 8; ++c) {
    int i = c * 128 + t;
    if (i >= 1) {
      int tk = W[b * S_ + i];
      cnt += ((tk != PAD_IDX) & (tk != EOS_IDX)) ? 1 : 0;
    }
  }

  float term = __expf(transitions[BOT_IDX * T_ + t]
                      + emissions[(size_t)b * S_ * T_ + t]) * qv[t];
  redf[t] = term;
  redi[t] = cnt;
  __syncthreads();
  #pragma unroll
  for (int off = 64; off > 0; off >>= 1) {
    if (t < off) { redf[t] += redf[t + off]; redi[t] += redi[t + off]; }
    __syncthreads();
  }
  if (t == 0) out[b] = GHAT * (float)redi[0] + logf(redf[0]);
}

extern "C" void kernel_launch(void* const* d_in, const int* in_sizes, int n_in,
                              void* d_out, int out_size, void* d_ws, size_t ws_size,
                              hipStream_t stream) {
  const int*   W     = (const int*)d_in[0];
  const float* em    = (const float*)d_in[1];
  const float* trans = (const float*)d_in[2];
  float*       out   = (float*)d_out;
  _Float16*    wsp   = (_Float16*)d_ws;          // needs 32 MB
  (void)in_sizes; (void)n_in; (void)out_size; (void)ws_size;

  crf_seg_kernel<<<dim3(B_, G_, 2), 256, 0, stream>>>(W, em, trans, wsp);
  crf_combine_kernel<<<B_, 128, 0, stream>>>(W, em, trans, wsp, out);
}